// Round 1
// baseline (301.099 us; speedup 1.0000x reference)
//
#include <hip/hip_runtime.h>
#include <stdint.h>

// Problem constants (fixed shapes from setup_inputs)
#define BB 4
#define CCH 32
#define HH 128
#define WW 128
#define SCALE 2
#define HO 256
#define WO 256
#define QQ (HO*WO)          // 65536 queries per batch
#define HWH (HH*WW)         // 16384
#define MT 64               // queries per workgroup
#define KPAD 264            // LDS activation row stride (bf16 elems): 256 + 8 pad

// Transposed bf16 weight layout offsets in d_ws (elements), each [N][KP] row-major
#define WOFF_L0 0           // [256][64]   (K=36 zero-padded to 64)
#define WOFF_L1 16384       // [256][256]
#define WOFF_L2 81920       // [32][256]
#define WOFF_R0 90112       // [256][32]
#define WOFF_R1 98304       // [32][256]
#define WOFF_O0 106496      // [256][32]
#define WOFF_O1 114688      // [16][256]  (N=2 zero-padded to 16)
#define WTOT    118784

typedef __attribute__((ext_vector_type(8))) __bf16 bf16x8;
typedef __attribute__((ext_vector_type(4))) float f32x4;

__device__ __forceinline__ unsigned short f2bf(float f) {
  union { float f; unsigned int u; } v; v.f = f;
  unsigned int u = v.u;
  u += 0x7fffu + ((u >> 16) & 1u);   // round-to-nearest-even
  return (unsigned short)(u >> 16);
}

// ---------------- weight prep: fp32 [K][N] -> bf16 [N][KP] (transposed, padded) ----
__global__ void prep_weights(const float* __restrict__ w0, const float* __restrict__ w1,
                             const float* __restrict__ w2, const float* __restrict__ r0,
                             const float* __restrict__ r1, const float* __restrict__ o0,
                             const float* __restrict__ o1, unsigned short* __restrict__ wt)
{
  int idx = blockIdx.x * 256 + threadIdx.x;
  if (idx >= WTOT) return;
  const float* src; int K, Nsrc, KP, base;
  if (idx < WOFF_L1)      { src = w0; K = 36;  Nsrc = 256; KP = 64;  base = WOFF_L0; }
  else if (idx < WOFF_L2) { src = w1; K = 256; Nsrc = 256; KP = 256; base = WOFF_L1; }
  else if (idx < WOFF_R0) { src = w2; K = 256; Nsrc = 32;  KP = 256; base = WOFF_L2; }
  else if (idx < WOFF_R1) { src = r0; K = 32;  Nsrc = 256; KP = 32;  base = WOFF_R0; }
  else if (idx < WOFF_O0) { src = r1; K = 256; Nsrc = 32;  KP = 256; base = WOFF_R1; }
  else if (idx < WOFF_O1) { src = o0; K = 32;  Nsrc = 256; KP = 32;  base = WOFF_O0; }
  else                    { src = o1; K = 256; Nsrc = 2;   KP = 256; base = WOFF_O1; }
  int local = idx - base;
  int n = local / KP, k = local % KP;
  float v = (k < K && n < Nsrc) ? src[k * Nsrc + n] : 0.f;
  wt[idx] = f2bf(v);
}

// ---------------- bicubic helpers (torch aten A=-0.75, align_corners=False, zero pad)
__device__ __forceinline__ void cubw(float t, float w[4]) {
  const float A = -0.75f;
  float x = t + 1.f;
  w[0] = ((A * x - 5.f * A) * x + 8.f * A) * x - 4.f * A;
  w[1] = ((A + 2.f) * t - (A + 3.f)) * t * t + 1.f;
  float s = 1.f - t;
  w[2] = ((A + 2.f) * s - (A + 3.f)) * s * s + 1.f;
  w[3] = 1.f - w[0] - w[1] - w[2];
}

// 8-channel bicubic sample at (gx,gy); also accumulates interpolated LR coord field.
__device__ __forceinline__ void bicubic8(const float* __restrict__ bptr, float gx, float gy,
                                         float feat[8], float& qcy, float& qcx)
{
  float ix = ((gx + 1.f) * (float)WW - 1.f) * 0.5f;
  float iy = ((gy + 1.f) * (float)HH - 1.f) * 0.5f;
  float fx0 = floorf(ix), fy0 = floorf(iy);
  float tx = ix - fx0, ty = iy - fy0;
  float wx[4], wy[4];
  cubw(tx, wx); cubw(ty, wy);
  int ix0 = (int)fx0, iy0 = (int)fy0;
  #pragma unroll
  for (int c = 0; c < 8; c++) feat[c] = 0.f;
  qcy = 0.f; qcx = 0.f;
  #pragma unroll
  for (int i = 0; i < 4; i++) {
    int yi = iy0 - 1 + i;
    bool yok = (yi >= 0) && (yi < HH);
    int yc = min(max(yi, 0), HH - 1);
    float yv = -1.f + (2.f * yc + 1.f) * (1.f / HH);
    #pragma unroll
    for (int j = 0; j < 4; j++) {
      int xj = ix0 - 1 + j;
      bool ok = yok && (xj >= 0) && (xj < WW);
      if (!ok) continue;                       // zero-padding: tap contributes 0
      int xc = min(max(xj, 0), WW - 1);
      float wv = wy[i] * wx[j];
      const float* p = bptr + yc * WW + xc;
      #pragma unroll
      for (int c = 0; c < 8; c++) feat[c] = fmaf(wv, p[c * HWH], feat[c]);
      qcy = fmaf(wv, yv, qcy);
      qcx = fmaf(wv, (-1.f + (2.f * xc + 1.f) * (1.f / WW)), qcx);
    }
  }
}

// ---------------- MFMA layer routines -------------------------------------------
// A-frag: A[m=lane&15][k=quad*8+j]; B-frag: B[k=quad*8+j][n=lane&15] from Wt[n][KP];
// C/D: row=quad*4+r, col=lane&15. (verified layouts, learn_hip m89/m91/m120)

// N=256: wave w owns n in [w*64, w*64+64) (4 n-tiles); loops all 4 m-tiles with
// B-frags held in registers across the K loop -> weights read once per wg.
template<int KP, bool RELU>
__device__ __forceinline__ void layer_n256(const unsigned short* lin, unsigned short* lout,
                                           const unsigned short* __restrict__ W,
                                           const float* __restrict__ bias, int w, int lane)
{
  int lm = lane & 15, quad = lane >> 4;
  int nbase = w * 64;
  f32x4 acc[4][4];
  #pragma unroll
  for (int nt = 0; nt < 4; nt++) {
    float bv = bias[nbase + nt * 16 + lm];
    f32x4 b4 = {bv, bv, bv, bv};
    #pragma unroll
    for (int mt = 0; mt < 4; mt++) acc[mt][nt] = b4;
  }
  #pragma unroll
  for (int kk = 0; kk < KP / 32; kk++) {
    bf16x8 bf[4];
    #pragma unroll
    for (int nt = 0; nt < 4; nt++)
      bf[nt] = *(const bf16x8*)(W + (nbase + nt * 16 + lm) * KP + kk * 32 + quad * 8);
    #pragma unroll
    for (int mt = 0; mt < 4; mt++) {
      bf16x8 af = *(const bf16x8*)(lin + (mt * 16 + lm) * KPAD + kk * 32 + quad * 8);
      #pragma unroll
      for (int nt = 0; nt < 4; nt++)
        acc[mt][nt] = __builtin_amdgcn_mfma_f32_16x16x32_bf16(af, bf[nt], acc[mt][nt], 0, 0, 0);
    }
  }
  #pragma unroll
  for (int mt = 0; mt < 4; mt++)
    #pragma unroll
    for (int nt = 0; nt < 4; nt++)
      #pragma unroll
      for (int r = 0; r < 4; r++) {
        float v = acc[mt][nt][r];
        if (RELU) v = fmaxf(v, 0.f);
        lout[(mt * 16 + quad * 4 + r) * KPAD + nbase + nt * 16 + lm] = f2bf(v);
      }
}

// N=32: waves (0,1) take m-tiles {0,1}, waves (2,3) take {2,3}; nt = w&1.
// EPI 0: bf16 -> lout (KPAD layout). EPI 1: fp32 -> fout ([64][33]).
template<int KP, bool RELU, int EPI>
__device__ __forceinline__ void layer_n32(const unsigned short* lin, unsigned short* lout,
                                          float* fout, const unsigned short* __restrict__ W,
                                          const float* __restrict__ bias, int w, int lane)
{
  int lm = lane & 15, quad = lane >> 4;
  int nt = w & 1, mtb = (w >> 1) * 2;
  float bv = bias[nt * 16 + lm];
  f32x4 acc[2];
  acc[0] = (f32x4){bv, bv, bv, bv};
  acc[1] = acc[0];
  #pragma unroll
  for (int kk = 0; kk < KP / 32; kk++) {
    bf16x8 bf = *(const bf16x8*)(W + (nt * 16 + lm) * KP + kk * 32 + quad * 8);
    #pragma unroll
    for (int mi = 0; mi < 2; mi++) {
      bf16x8 af = *(const bf16x8*)(lin + ((mtb + mi) * 16 + lm) * KPAD + kk * 32 + quad * 8);
      acc[mi] = __builtin_amdgcn_mfma_f32_16x16x32_bf16(af, bf, acc[mi], 0, 0, 0);
    }
  }
  #pragma unroll
  for (int mi = 0; mi < 2; mi++)
    #pragma unroll
    for (int r = 0; r < 4; r++) {
      float v = acc[mi][r];
      if (RELU) v = fmaxf(v, 0.f);
      int row = (mtb + mi) * 16 + quad * 4 + r, col = nt * 16 + lm;
      if (EPI == 0) lout[row * KPAD + col] = f2bf(v);
      else          fout[row * 33 + col] = v;
    }
}

// Offset head: N padded to 16 (cols 2..15 are zero weights); wave w -> m-tile w.
__device__ __forceinline__ void layer_off(const unsigned short* lin, float* offb,
                                          const unsigned short* __restrict__ W,
                                          const float* __restrict__ bias, int w, int lane)
{
  int lm = lane & 15, quad = lane >> 4;
  float bv = (lm < 2) ? bias[lm] : 0.f;
  f32x4 acc = {bv, bv, bv, bv};
  #pragma unroll
  for (int kk = 0; kk < 8; kk++) {
    bf16x8 bf = *(const bf16x8*)(W + lm * 256 + kk * 32 + quad * 8);
    bf16x8 af = *(const bf16x8*)(lin + (w * 16 + lm) * KPAD + kk * 32 + quad * 8);
    acc = __builtin_amdgcn_mfma_f32_16x16x32_bf16(af, bf, acc, 0, 0, 0);
  }
  if (lm < 2) {
    #pragma unroll
    for (int r = 0; r < 4; r++) offb[(w * 16 + quad * 4 + r) * 2 + lm] = acc[r];
  }
}

// ---------------- fused LIIF kernel ----------------------------------------------
__launch_bounds__(256, 2)
__global__ void liif_fused(const float* __restrict__ x, const unsigned short* __restrict__ wt,
                           const float* __restrict__ b0, const float* __restrict__ b1,
                           const float* __restrict__ b2, const float* __restrict__ rb0,
                           const float* __restrict__ rb1, const float* __restrict__ ob0,
                           const float* __restrict__ ob1, float* __restrict__ out)
{
  __shared__ __align__(16) unsigned short bufA[MT * KPAD];
  __shared__ __align__(16) unsigned short bufB[MT * KPAD];
  __shared__ float routbuf[MT * 33];
  __shared__ float offb[MT * 2];
  __shared__ float gxy[MT * 2];

  int t = threadIdx.x;
  int ql = t & 63;            // lane == local query
  int g = t >> 6;             // wave id == 8-channel group
  int q = blockIdx.x * MT + ql;
  int b = q >> 16;            // / QQ
  int qi = q & (QQ - 1);
  int oy = qi >> 8;           // / WO
  int ox = qi & (WO - 1);

  float coordy = -1.f + (2.f * oy + 1.f) * (1.f / HO);
  float coordx = -1.f + (2.f * ox + 1.f) * (1.f / WO);
  float gy = fminf(fmaxf(coordy, -1.f + 1e-6f), 1.f - 1e-6f);
  float gx = fminf(fmaxf(coordx, -1.f + 1e-6f), 1.f - 1e-6f);

  const float* bptr = x + (b * CCH + g * 8) * HWH;

  // ---- phase 0: bicubic q_feat + analytic q_coord -> LDS bf16 input [64][36->64]
  {
    float feat[8], qcy, qcx;
    bicubic8(bptr, gx, gy, feat, qcy, qcx);
    union { unsigned short u[8]; bf16x8 v; } pk;
    #pragma unroll
    for (int c = 0; c < 8; c++) pk.u[c] = f2bf(feat[c]);
    *(bf16x8*)&bufA[ql * KPAD + g * 8] = pk.v;
    if (g == 0) {
      gxy[ql * 2 + 0] = gx;
      gxy[ql * 2 + 1] = gy;
      float rcy = (coordy - qcy) * (float)HH;
      float rcx = (coordx - qcx) * (float)WW;
      // faithful LIIF-quirk: cell[:,0] (query 0) *= 2/Ho ; cell[:,1] (query 1) *= 2/Wo
      float m = (qi == 0) ? (2.f / HO) : (qi == 1) ? (2.f / WO) : 1.f;
      bufA[ql * KPAD + 32] = f2bf(rcy);
      bufA[ql * KPAD + 33] = f2bf(rcx);
      bufA[ql * KPAD + 34] = f2bf(m * (float)HH);
      bufA[ql * KPAD + 35] = f2bf(m * (float)WW);
      for (int k = 36; k < 64; k++) bufA[ql * KPAD + k] = 0;
    }
  }
  __syncthreads();

  // ---- MLP chain (ping-pong LDS, pred parked in bufB for both heads)
  layer_n256<64, true>(bufA, bufB, wt + WOFF_L0, b0, g, ql);   // inp -> h0
  __syncthreads();
  layer_n256<256, true>(bufB, bufA, wt + WOFF_L1, b1, g, ql);  // h0 -> h1
  __syncthreads();
  layer_n32<256, false, 0>(bufA, bufB, nullptr, wt + WOFF_L2, b2, g, ql);  // h1 -> pred
  __syncthreads();
  layer_n256<32, true>(bufB, bufA, wt + WOFF_R0, rb0, g, ql);  // pred -> r0
  __syncthreads();
  layer_n32<256, false, 1>(bufA, nullptr, routbuf, wt + WOFF_R1, rb1, g, ql); // r0 -> routing
  __syncthreads();
  layer_n256<32, true>(bufB, bufA, wt + WOFF_O0, ob0, g, ql);  // pred -> o0
  __syncthreads();
  layer_off(bufA, offb, wt + WOFF_O1, ob1, g, ql);             // o0 -> off
  __syncthreads();

  // ---- final: resample at offset coords, modulate by routing, store
  {
    float gx2 = gxy[ql * 2 + 0] + offb[ql * 2 + 0];
    float gy2 = gxy[ql * 2 + 1] + offb[ql * 2 + 1];
    float feat[8], d0, d1;
    bicubic8(bptr, gx2, gy2, feat, d0, d1);
    float* op = out + (b * CCH + g * 8) * (HO * WO) + oy * WO + ox;
    #pragma unroll
    for (int c = 0; c < 8; c++)
      op[c * (HO * WO)] = feat[c] * (1.f + routbuf[ql * 33 + g * 8 + c]);
  }
}

extern "C" void kernel_launch(void* const* d_in, const int* in_sizes, int n_in,
                              void* d_out, int out_size, void* d_ws, size_t ws_size,
                              hipStream_t stream)
{
  const float* x   = (const float*)d_in[0];
  const float* w0  = (const float*)d_in[1];
  const float* b0  = (const float*)d_in[2];
  const float* w1  = (const float*)d_in[3];
  const float* b1  = (const float*)d_in[4];
  const float* w2  = (const float*)d_in[5];
  const float* b2  = (const float*)d_in[6];
  const float* r0  = (const float*)d_in[7];
  const float* rb0 = (const float*)d_in[8];
  const float* r1  = (const float*)d_in[9];
  const float* rb1 = (const float*)d_in[10];
  const float* o0  = (const float*)d_in[11];
  const float* ob0 = (const float*)d_in[12];
  const float* o1  = (const float*)d_in[13];
  const float* ob1 = (const float*)d_in[14];
  unsigned short* wt = (unsigned short*)d_ws;
  float* out = (float*)d_out;

  prep_weights<<<(WTOT + 255) / 256, 256, 0, stream>>>(w0, w1, w2, r0, r1, o0, o1, wt);
  liif_fused<<<(BB * QQ) / MT, 256, 0, stream>>>(x, wt, b0, b1, b2, rb0, rb1, ob0, ob1, out);
}

// Round 3
// 282.340 us; speedup vs baseline: 1.0664x; 1.0664x over previous
//
#include <hip/hip_runtime.h>
#include <stdint.h>

// Problem constants (fixed shapes from setup_inputs)
#define BB 4
#define CCH 32
#define HH 128
#define WW 128
#define SCALE 2
#define HO 256
#define WO 256
#define QQ (HO*WO)          // 65536 queries per batch
#define HWH (HH*WW)         // 16384
#define MT 64               // queries per workgroup
#define KPAD 264            // main LDS activation row stride (bf16 elems): 256 + 8 pad
#define PSTR 40             // pred buffer row stride (bf16 elems): 32 + 8 pad (80 B = 16B-aligned rows)

// Transposed bf16 weight layout offsets in d_ws (elements), each [N][KP] row-major
#define WOFF_L0 0           // [256][64]   (K=36 zero-padded to 64)
#define WOFF_L1 16384       // [256][256]
#define WOFF_L2 81920       // [32][256]
#define WOFF_R0 90112       // [256][32]
#define WOFF_R1 98304       // [32][256]
#define WOFF_O0 106496      // [256][32]
#define WOFF_O1 114688      // [16][256]  (N=2 zero-padded to 16)
#define WTOT    118784

typedef __attribute__((ext_vector_type(8))) __bf16 bf16x8;
typedef __attribute__((ext_vector_type(4))) float f32x4;

// Software f32->bf16 round-to-nearest-even. PROVEN in R1 (absmax 0.031).
// NOTE: R2's v_cvt_pk_bf16_f32 inline asm produced NaN on gfx950 — do not reintroduce
// without an isolated correctness probe (suspected partial-dst write / stale hi bits).
__device__ __forceinline__ unsigned short f2bf(float f) {
  union { float f; unsigned int u; } v; v.f = f;
  unsigned int u = v.u;
  u += 0x7fffu + ((u >> 16) & 1u);
  return (unsigned short)(u >> 16);
}

// ---------------- weight prep: fp32 [K][N] -> bf16 [N][KP] (transposed, padded) ----
__global__ void prep_weights(const float* __restrict__ w0, const float* __restrict__ w1,
                             const float* __restrict__ w2, const float* __restrict__ r0,
                             const float* __restrict__ r1, const float* __restrict__ o0,
                             const float* __restrict__ o1, unsigned short* __restrict__ wt)
{
  int idx = blockIdx.x * 256 + threadIdx.x;
  if (idx >= WTOT) return;
  const float* src; int K, Nsrc, KP, base;
  if (idx < WOFF_L1)      { src = w0; K = 36;  Nsrc = 256; KP = 64;  base = WOFF_L0; }
  else if (idx < WOFF_L2) { src = w1; K = 256; Nsrc = 256; KP = 256; base = WOFF_L1; }
  else if (idx < WOFF_R0) { src = w2; K = 256; Nsrc = 32;  KP = 256; base = WOFF_L2; }
  else if (idx < WOFF_R1) { src = r0; K = 32;  Nsrc = 256; KP = 32;  base = WOFF_R0; }
  else if (idx < WOFF_O0) { src = r1; K = 256; Nsrc = 32;  KP = 256; base = WOFF_R1; }
  else if (idx < WOFF_O1) { src = o0; K = 32;  Nsrc = 256; KP = 32;  base = WOFF_O0; }
  else                    { src = o1; K = 256; Nsrc = 2;   KP = 256; base = WOFF_O1; }
  int local = idx - base;
  int n = local / KP, k = local % KP;
  float v = (k < K && n < Nsrc) ? src[k * Nsrc + n] : 0.f;
  wt[idx] = f2bf(v);
}

// ---------------- bicubic helpers (torch aten A=-0.75, align_corners=False, zero pad)
__device__ __forceinline__ void cubw(float t, float w[4]) {
  const float A = -0.75f;
  float x = t + 1.f;
  w[0] = ((A * x - 5.f * A) * x + 8.f * A) * x - 4.f * A;
  w[1] = ((A + 2.f) * t - (A + 3.f)) * t * t + 1.f;
  float s = 1.f - t;
  w[2] = ((A + 2.f) * s - (A + 3.f)) * s * s + 1.f;
  w[3] = 1.f - w[0] - w[1] - w[2];
}

// 8-channel bicubic sample at (gx,gy); also accumulates interpolated LR coord field.
__device__ __forceinline__ void bicubic8(const float* __restrict__ bptr, float gx, float gy,
                                         float feat[8], float& qcy, float& qcx)
{
  float ix = ((gx + 1.f) * (float)WW - 1.f) * 0.5f;
  float iy = ((gy + 1.f) * (float)HH - 1.f) * 0.5f;
  float fx0 = floorf(ix), fy0 = floorf(iy);
  float tx = ix - fx0, ty = iy - fy0;
  float wx[4], wy[4];
  cubw(tx, wx); cubw(ty, wy);
  int ix0 = (int)fx0, iy0 = (int)fy0;
  #pragma unroll
  for (int c = 0; c < 8; c++) feat[c] = 0.f;
  qcy = 0.f; qcx = 0.f;
  #pragma unroll
  for (int i = 0; i < 4; i++) {
    int yi = iy0 - 1 + i;
    bool yok = (yi >= 0) && (yi < HH);
    int yc = min(max(yi, 0), HH - 1);
    float yv = -1.f + (2.f * yc + 1.f) * (1.f / HH);
    #pragma unroll
    for (int j = 0; j < 4; j++) {
      int xj = ix0 - 1 + j;
      bool ok = yok && (xj >= 0) && (xj < WW);
      if (!ok) continue;                       // zero-padding: tap contributes 0
      int xc = min(max(xj, 0), WW - 1);
      float wv = wy[i] * wx[j];
      const float* p = bptr + yc * WW + xc;
      #pragma unroll
      for (int c = 0; c < 8; c++) feat[c] = fmaf(wv, p[c * HWH], feat[c]);
      qcy = fmaf(wv, yv, qcy);
      qcx = fmaf(wv, (-1.f + (2.f * xc + 1.f) * (1.f / WW)), qcx);
    }
  }
}

// ---------------- MFMA layer routines -------------------------------------------
// A-frag: A[m=lane&15][k=quad*8+j]; B-frag: B[k=quad*8+j][n=lane&15] from Wt[n][KP];
// C/D: row=quad*4+r, col=lane&15. (verified layouts, learn_hip m89/m91/m120)

// N=256: wave w owns n in [w*64, w*64+64) (4 n-tiles); loops all 4 m-tiles with
// B-frags held in registers across the K loop -> weights read once per wg.
// INPLACE: output overwrites the input buffer; internal barrier orders all waves'
// A-frag reads before any epilogue write (accumulators ride in registers across it).
template<int KP, int LSTRIDE, bool RELU, bool INPLACE>
__device__ __forceinline__ void layer_n256(const unsigned short* lin, unsigned short* lout,
                                           const unsigned short* __restrict__ W,
                                           const float* __restrict__ bias, int w, int lane)
{
  int lm = lane & 15, quad = lane >> 4;
  int nbase = w * 64;
  f32x4 acc[4][4];
  #pragma unroll
  for (int nt = 0; nt < 4; nt++) {
    float bv = bias[nbase + nt * 16 + lm];
    f32x4 b4 = {bv, bv, bv, bv};
    #pragma unroll
    for (int mt = 0; mt < 4; mt++) acc[mt][nt] = b4;
  }
  #pragma unroll
  for (int kk = 0; kk < KP / 32; kk++) {
    bf16x8 bf[4];
    #pragma unroll
    for (int nt = 0; nt < 4; nt++)
      bf[nt] = *(const bf16x8*)(W + (nbase + nt * 16 + lm) * KP + kk * 32 + quad * 8);
    #pragma unroll
    for (int mt = 0; mt < 4; mt++) {
      bf16x8 af = *(const bf16x8*)(lin + (mt * 16 + lm) * LSTRIDE + kk * 32 + quad * 8);
      #pragma unroll
      for (int nt = 0; nt < 4; nt++)
        acc[mt][nt] = __builtin_amdgcn_mfma_f32_16x16x32_bf16(af, bf[nt], acc[mt][nt], 0, 0, 0);
    }
  }
  if (INPLACE) __syncthreads();   // all waves' reads of lin complete before overwrite
  #pragma unroll
  for (int mt = 0; mt < 4; mt++)
    #pragma unroll
    for (int nt = 0; nt < 4; nt++) {
      int col = nbase + nt * 16 + lm;
      #pragma unroll
      for (int r = 0; r < 4; r++) {
        float v = acc[mt][nt][r];
        if (RELU) v = fmaxf(v, 0.f);
        lout[(mt * 16 + quad * 4 + r) * KPAD + col] = f2bf(v);
      }
    }
}

// N=32: waves (0,1) take m-tiles {0,1}, waves (2,3) take {2,3}; nt = w&1.
// EPI 0: bf16 -> lout (PSTR layout, pred buffer). EPI 1: fp32 -> fout ([64][33]).
template<int KP, bool RELU, int EPI>
__device__ __forceinline__ void layer_n32(const unsigned short* lin, unsigned short* lout,
                                          float* fout, const unsigned short* __restrict__ W,
                                          const float* __restrict__ bias, int w, int lane)
{
  int lm = lane & 15, quad = lane >> 4;
  int nt = w & 1, mtb = (w >> 1) * 2;
  float bv = bias[nt * 16 + lm];
  f32x4 acc[2];
  acc[0] = (f32x4){bv, bv, bv, bv};
  acc[1] = acc[0];
  #pragma unroll
  for (int kk = 0; kk < KP / 32; kk++) {
    bf16x8 bf = *(const bf16x8*)(W + (nt * 16 + lm) * KP + kk * 32 + quad * 8);
    #pragma unroll
    for (int mi = 0; mi < 2; mi++) {
      bf16x8 af = *(const bf16x8*)(lin + ((mtb + mi) * 16 + lm) * KPAD + kk * 32 + quad * 8);
      acc[mi] = __builtin_amdgcn_mfma_f32_16x16x32_bf16(af, bf, acc[mi], 0, 0, 0);
    }
  }
  #pragma unroll
  for (int mi = 0; mi < 2; mi++) {
    int row0 = (mtb + mi) * 16 + quad * 4, col = nt * 16 + lm;
    #pragma unroll
    for (int r = 0; r < 4; r++) {
      float v = acc[mi][r];
      if (RELU) v = fmaxf(v, 0.f);
      if (EPI == 0) lout[(row0 + r) * PSTR + col] = f2bf(v);
      else          fout[(row0 + r) * 33 + col] = v;
    }
  }
}

// Offset head: N padded to 16 (cols 2..15 are zero weights); wave w -> m-tile w.
__device__ __forceinline__ void layer_off(const unsigned short* lin, float* offb,
                                          const unsigned short* __restrict__ W,
                                          const float* __restrict__ bias, int w, int lane)
{
  int lm = lane & 15, quad = lane >> 4;
  float bv = (lm < 2) ? bias[lm] : 0.f;
  f32x4 acc = {bv, bv, bv, bv};
  #pragma unroll
  for (int kk = 0; kk < 8; kk++) {
    bf16x8 bf = *(const bf16x8*)(W + lm * 256 + kk * 32 + quad * 8);
    bf16x8 af = *(const bf16x8*)(lin + (w * 16 + lm) * KPAD + kk * 32 + quad * 8);
    acc = __builtin_amdgcn_mfma_f32_16x16x32_bf16(af, bf, acc, 0, 0, 0);
  }
  if (lm < 2) {
    #pragma unroll
    for (int r = 0; r < 4; r++) offb[(w * 16 + quad * 4 + r) * 2 + lm] = acc[r];
  }
}

// ---------------- fused LIIF kernel ----------------------------------------------
// Single in-place activation buffer (acc lives in registers across the read->write
// barrier) -> LDS 48.4 KB -> 3 blocks/CU instead of 2.
__launch_bounds__(256, 3)
__global__ void liif_fused(const float* __restrict__ x, const unsigned short* __restrict__ wt,
                           const float* __restrict__ b0, const float* __restrict__ b1,
                           const float* __restrict__ b2, const float* __restrict__ rb0,
                           const float* __restrict__ rb1, const float* __restrict__ ob0,
                           const float* __restrict__ ob1, float* __restrict__ out)
{
  __shared__ __align__(16) unsigned short act[MT * KPAD];    // 33792 B
  __shared__ __align__(16) unsigned short predb[MT * PSTR];  // 5120 B
  __shared__ float routbuf[MT * 33];                         // 8448 B
  __shared__ float offb[MT * 2];
  __shared__ float gxy[MT * 2];

  int t = threadIdx.x;
  int ql = t & 63;            // lane == local query
  int g = t >> 6;             // wave id == 8-channel group
  int q = blockIdx.x * MT + ql;
  int b = q >> 16;            // / QQ
  int qi = q & (QQ - 1);
  int oy = qi >> 8;           // / WO
  int ox = qi & (WO - 1);

  float coordy = -1.f + (2.f * oy + 1.f) * (1.f / HO);
  float coordx = -1.f + (2.f * ox + 1.f) * (1.f / WO);
  float gy = fminf(fmaxf(coordy, -1.f + 1e-6f), 1.f - 1e-6f);
  float gx = fminf(fmaxf(coordx, -1.f + 1e-6f), 1.f - 1e-6f);

  const float* bptr = x + (b * CCH + g * 8) * HWH;

  // ---- phase 0: bicubic q_feat + analytic q_coord -> LDS bf16 input [64][36->64]
  // (exact R1-proven write path)
  {
    float feat[8], qcy, qcx;
    bicubic8(bptr, gx, gy, feat, qcy, qcx);
    union { unsigned short u[8]; bf16x8 v; } pk;
    #pragma unroll
    for (int c = 0; c < 8; c++) pk.u[c] = f2bf(feat[c]);
    *(bf16x8*)&act[ql * KPAD + g * 8] = pk.v;
    if (g == 0) {
      gxy[ql * 2 + 0] = gx;
      gxy[ql * 2 + 1] = gy;
      float rcy = (coordy - qcy) * (float)HH;
      float rcx = (coordx - qcx) * (float)WW;
      // faithful LIIF-quirk: cell[:,0] (query 0) *= 2/Ho ; cell[:,1] (query 1) *= 2/Wo
      float m = (qi == 0) ? (2.f / HO) : (qi == 1) ? (2.f / WO) : 1.f;
      act[ql * KPAD + 32] = f2bf(rcy);
      act[ql * KPAD + 33] = f2bf(rcx);
      act[ql * KPAD + 34] = f2bf(m * (float)HH);
      act[ql * KPAD + 35] = f2bf(m * (float)WW);
      for (int k = 36; k < 64; k++) act[ql * KPAD + k] = 0;
    }
  }
  __syncthreads();                                                        // B0

  // ---- MLP chain, single in-place activation buffer
  layer_n256<64, KPAD, true, true>(act, act, wt + WOFF_L0, b0, g, ql);    // inp -> h0
  __syncthreads();                                                        // B1
  layer_n256<256, KPAD, true, true>(act, act, wt + WOFF_L1, b1, g, ql);   // h0 -> h1
  __syncthreads();                                                        // B2
  layer_n32<256, false, 0>(act, predb, nullptr, wt + WOFF_L2, b2, g, ql); // h1 -> pred
  __syncthreads();                                                        // B3
  layer_n256<32, PSTR, true, false>(predb, act, wt + WOFF_R0, rb0, g, ql); // pred -> r0
  __syncthreads();                                                        // B4
  layer_n32<256, false, 1>(act, nullptr, routbuf, wt + WOFF_R1, rb1, g, ql); // r0 -> routing
  __syncthreads();                                                        // B5
  layer_n256<32, PSTR, true, false>(predb, act, wt + WOFF_O0, ob0, g, ql); // pred -> o0
  __syncthreads();                                                        // B6
  layer_off(act, offb, wt + WOFF_O1, ob1, g, ql);                         // o0 -> off
  __syncthreads();                                                        // B7

  // ---- final: resample at offset coords, modulate by routing, store
  {
    float gx2 = gxy[ql * 2 + 0] + offb[ql * 2 + 0];
    float gy2 = gxy[ql * 2 + 1] + offb[ql * 2 + 1];
    float feat[8], d0, d1;
    bicubic8(bptr, gx2, gy2, feat, d0, d1);
    float* op = out + (b * CCH + g * 8) * (HO * WO) + oy * WO + ox;
    #pragma unroll
    for (int c = 0; c < 8; c++)
      op[c * (HO * WO)] = feat[c] * (1.f + routbuf[ql * 33 + g * 8 + c]);
  }
}

extern "C" void kernel_launch(void* const* d_in, const int* in_sizes, int n_in,
                              void* d_out, int out_size, void* d_ws, size_t ws_size,
                              hipStream_t stream)
{
  const float* x   = (const float*)d_in[0];
  const float* w0  = (const float*)d_in[1];
  const float* b0  = (const float*)d_in[2];
  const float* w1  = (const float*)d_in[3];
  const float* b1  = (const float*)d_in[4];
  const float* w2  = (const float*)d_in[5];
  const float* b2  = (const float*)d_in[6];
  const float* r0  = (const float*)d_in[7];
  const float* rb0 = (const float*)d_in[8];
  const float* r1  = (const float*)d_in[9];
  const float* rb1 = (const float*)d_in[10];
  const float* o0  = (const float*)d_in[11];
  const float* ob0 = (const float*)d_in[12];
  const float* o1  = (const float*)d_in[13];
  const float* ob1 = (const float*)d_in[14];
  unsigned short* wt = (unsigned short*)d_ws;
  float* out = (float*)d_out;

  prep_weights<<<(WTOT + 255) / 256, 256, 0, stream>>>(w0, w1, w2, r0, r1, o0, o1, wt);
  liif_fused<<<(BB * QQ) / MT, 256, 0, stream>>>(x, wt, b0, b1, b2, rb0, rb1, ob0, ob1, out);
}

// Round 4
// 278.207 us; speedup vs baseline: 1.0823x; 1.0149x over previous
//
#include <hip/hip_runtime.h>
#include <hip/hip_bf16.h>
#include <stdint.h>

// Problem constants (fixed shapes from setup_inputs)
#define BB 4
#define CCH 32
#define HH 128
#define WW 128
#define SCALE 2
#define HO 256
#define WO 256
#define QQ (HO*WO)          // 65536 queries per batch
#define HWH (HH*WW)         // 16384
#define MT 64               // queries per workgroup
#define KPAD 264            // main LDS activation row stride (bf16 elems): 256 + 8 pad
#define PSTR 40             // pred buffer row stride (bf16 elems): 32 + 8 pad (80 B = 16B-aligned rows)

// Transposed bf16 weight layout offsets in d_ws (elements), each [N][KP] row-major
#define WOFF_L0 0           // [256][64]   (K=36 zero-padded to 64)
#define WOFF_L1 16384       // [256][256]
#define WOFF_L2 81920       // [32][256]
#define WOFF_R0 90112       // [256][32]
#define WOFF_R1 98304       // [32][256]
#define WOFF_O0 106496      // [256][32]
#define WOFF_O1 114688      // [16][256]  (N=2 zero-padded to 16)
#define WTOT    118784

typedef __attribute__((ext_vector_type(8))) __bf16 bf16x8;
typedef __attribute__((ext_vector_type(4))) float f32x4;

// Software f32->bf16 round-to-nearest-even (cold paths only).
// NOTE: R2's hand-rolled v_cvt_pk_bf16_f32 inline asm produced NaN on gfx950;
// hot paths now use the header intrinsic __float22bfloat162_rn (R4), which the
// compiler lowers with correct register semantics.
__device__ __forceinline__ unsigned short f2bf(float f) {
  union { float f; unsigned int u; } v; v.f = f;
  unsigned int u = v.u;
  u += 0x7fffu + ((u >> 16) & 1u);
  return (unsigned short)(u >> 16);
}

// Packed f32x2 -> bf16x2 via hip_bf16 header (1 HW instr on gfx950, RNE).
__device__ __forceinline__ uint32_t pkbf(float a, float b) {
  union { __hip_bfloat162 h; uint32_t u; } cv;
  cv.h = __float22bfloat162_rn(make_float2(a, b));
  return cv.u;
}

// ---------------- weight prep: fp32 [K][N] -> bf16 [N][KP] (transposed, padded) ----
__global__ void prep_weights(const float* __restrict__ w0, const float* __restrict__ w1,
                             const float* __restrict__ w2, const float* __restrict__ r0,
                             const float* __restrict__ r1, const float* __restrict__ o0,
                             const float* __restrict__ o1, unsigned short* __restrict__ wt)
{
  int idx = blockIdx.x * 256 + threadIdx.x;
  if (idx >= WTOT) return;
  const float* src; int K, Nsrc, KP, base;
  if (idx < WOFF_L1)      { src = w0; K = 36;  Nsrc = 256; KP = 64;  base = WOFF_L0; }
  else if (idx < WOFF_L2) { src = w1; K = 256; Nsrc = 256; KP = 256; base = WOFF_L1; }
  else if (idx < WOFF_R0) { src = w2; K = 256; Nsrc = 32;  KP = 256; base = WOFF_L2; }
  else if (idx < WOFF_R1) { src = r0; K = 32;  Nsrc = 256; KP = 32;  base = WOFF_R0; }
  else if (idx < WOFF_O0) { src = r1; K = 256; Nsrc = 32;  KP = 256; base = WOFF_R1; }
  else if (idx < WOFF_O1) { src = o0; K = 32;  Nsrc = 256; KP = 32;  base = WOFF_O0; }
  else                    { src = o1; K = 256; Nsrc = 2;   KP = 256; base = WOFF_O1; }
  int local = idx - base;
  int n = local / KP, k = local % KP;
  float v = (k < K && n < Nsrc) ? src[k * Nsrc + n] : 0.f;
  wt[idx] = f2bf(v);
}

// ---------------- bicubic helpers (torch aten A=-0.75, align_corners=False, zero pad)
__device__ __forceinline__ void cubw(float t, float w[4]) {
  const float A = -0.75f;
  float x = t + 1.f;
  w[0] = ((A * x - 5.f * A) * x + 8.f * A) * x - 4.f * A;
  w[1] = ((A + 2.f) * t - (A + 3.f)) * t * t + 1.f;
  float s = 1.f - t;
  w[2] = ((A + 2.f) * s - (A + 3.f)) * s * s + 1.f;
  w[3] = 1.f - w[0] - w[1] - w[2];
}

// 8-channel bicubic sample at (gx,gy); also accumulates interpolated LR coord field.
__device__ __forceinline__ void bicubic8(const float* __restrict__ bptr, float gx, float gy,
                                         float feat[8], float& qcy, float& qcx)
{
  float ix = ((gx + 1.f) * (float)WW - 1.f) * 0.5f;
  float iy = ((gy + 1.f) * (float)HH - 1.f) * 0.5f;
  float fx0 = floorf(ix), fy0 = floorf(iy);
  float tx = ix - fx0, ty = iy - fy0;
  float wx[4], wy[4];
  cubw(tx, wx); cubw(ty, wy);
  int ix0 = (int)fx0, iy0 = (int)fy0;
  #pragma unroll
  for (int c = 0; c < 8; c++) feat[c] = 0.f;
  qcy = 0.f; qcx = 0.f;
  #pragma unroll
  for (int i = 0; i < 4; i++) {
    int yi = iy0 - 1 + i;
    bool yok = (yi >= 0) && (yi < HH);
    int yc = min(max(yi, 0), HH - 1);
    float yv = -1.f + (2.f * yc + 1.f) * (1.f / HH);
    #pragma unroll
    for (int j = 0; j < 4; j++) {
      int xj = ix0 - 1 + j;
      bool ok = yok && (xj >= 0) && (xj < WW);
      if (!ok) continue;                       // zero-padding: tap contributes 0
      int xc = min(max(xj, 0), WW - 1);
      float wv = wy[i] * wx[j];
      const float* p = bptr + yc * WW + xc;
      #pragma unroll
      for (int c = 0; c < 8; c++) feat[c] = fmaf(wv, p[c * HWH], feat[c]);
      qcy = fmaf(wv, yv, qcy);
      qcx = fmaf(wv, (-1.f + (2.f * xc + 1.f) * (1.f / WW)), qcx);
    }
  }
}

// ---------------- MFMA layer routines -------------------------------------------
// A-frag: A[m=lane&15][k=quad*8+j]; B-frag: B[k=quad*8+j][n=lane&15] from Wt[n][KP];
// C/D: row=quad*4+r, col=lane&15. (verified layouts, learn_hip m89/m91/m120)

// N=256: wave w owns n in [w*64, w*64+64) (4 n-tiles); loops all 4 m-tiles with
// B-frags held in registers across the K loop -> weights read once per wg.
// INPLACE: output overwrites the input buffer; internal barrier orders all waves'
// A-frag reads before any epilogue write (accumulators ride in registers across it).
template<int KP, int LSTRIDE, bool RELU, bool INPLACE>
__device__ __forceinline__ void layer_n256(const unsigned short* lin, unsigned short* lout,
                                           const unsigned short* __restrict__ W,
                                           const float* __restrict__ bias, int w, int lane)
{
  int lm = lane & 15, quad = lane >> 4;
  int nbase = w * 64;
  f32x4 acc[4][4];
  #pragma unroll
  for (int nt = 0; nt < 4; nt++) {
    float bv = bias[nbase + nt * 16 + lm];
    f32x4 b4 = {bv, bv, bv, bv};
    #pragma unroll
    for (int mt = 0; mt < 4; mt++) acc[mt][nt] = b4;
  }
  #pragma unroll
  for (int kk = 0; kk < KP / 32; kk++) {
    bf16x8 bf[4];
    #pragma unroll
    for (int nt = 0; nt < 4; nt++)
      bf[nt] = *(const bf16x8*)(W + (nbase + nt * 16 + lm) * KP + kk * 32 + quad * 8);
    #pragma unroll
    for (int mt = 0; mt < 4; mt++) {
      bf16x8 af = *(const bf16x8*)(lin + (mt * 16 + lm) * LSTRIDE + kk * 32 + quad * 8);
      #pragma unroll
      for (int nt = 0; nt < 4; nt++)
        acc[mt][nt] = __builtin_amdgcn_mfma_f32_16x16x32_bf16(af, bf[nt], acc[mt][nt], 0, 0, 0);
    }
  }
  if (INPLACE) __syncthreads();   // all waves' reads of lin complete before overwrite
  #pragma unroll
  for (int mt = 0; mt < 4; mt++)
    #pragma unroll
    for (int nt = 0; nt < 4; nt++) {
      int col = nbase + nt * 16 + lm;
      unsigned short* base = lout + (mt * 16 + quad * 4) * KPAD + col;
      #pragma unroll
      for (int r = 0; r < 4; r += 2) {
        float v0 = acc[mt][nt][r], v1 = acc[mt][nt][r + 1];
        if (RELU) { v0 = fmaxf(v0, 0.f); v1 = fmaxf(v1, 0.f); }
        uint32_t p = pkbf(v0, v1);
        base[r * KPAD]       = (unsigned short)p;
        base[(r + 1) * KPAD] = (unsigned short)(p >> 16);
      }
    }
}

// N=32: waves (0,1) take m-tiles {0,1}, waves (2,3) take {2,3}; nt = w&1.
// EPI 0: bf16 -> lout (PSTR layout, pred buffer). EPI 1: fp32 -> fout ([64][33]).
template<int KP, bool RELU, int EPI>
__device__ __forceinline__ void layer_n32(const unsigned short* lin, unsigned short* lout,
                                          float* fout, const unsigned short* __restrict__ W,
                                          const float* __restrict__ bias, int w, int lane)
{
  int lm = lane & 15, quad = lane >> 4;
  int nt = w & 1, mtb = (w >> 1) * 2;
  float bv = bias[nt * 16 + lm];
  f32x4 acc[2];
  acc[0] = (f32x4){bv, bv, bv, bv};
  acc[1] = acc[0];
  #pragma unroll
  for (int kk = 0; kk < KP / 32; kk++) {
    bf16x8 bf = *(const bf16x8*)(W + (nt * 16 + lm) * KP + kk * 32 + quad * 8);
    #pragma unroll
    for (int mi = 0; mi < 2; mi++) {
      bf16x8 af = *(const bf16x8*)(lin + ((mtb + mi) * 16 + lm) * KPAD + kk * 32 + quad * 8);
      acc[mi] = __builtin_amdgcn_mfma_f32_16x16x32_bf16(af, bf, acc[mi], 0, 0, 0);
    }
  }
  #pragma unroll
  for (int mi = 0; mi < 2; mi++) {
    int row0 = (mtb + mi) * 16 + quad * 4, col = nt * 16 + lm;
    if (EPI == 0) {
      #pragma unroll
      for (int r = 0; r < 4; r += 2) {
        float v0 = acc[mi][r], v1 = acc[mi][r + 1];
        if (RELU) { v0 = fmaxf(v0, 0.f); v1 = fmaxf(v1, 0.f); }
        uint32_t p = pkbf(v0, v1);
        lout[(row0 + r) * PSTR + col]     = (unsigned short)p;
        lout[(row0 + r + 1) * PSTR + col] = (unsigned short)(p >> 16);
      }
    } else {
      #pragma unroll
      for (int r = 0; r < 4; r++) {
        float v = acc[mi][r];
        if (RELU) v = fmaxf(v, 0.f);
        fout[(row0 + r) * 33 + col] = v;
      }
    }
  }
}

// Offset head: N padded to 16 (cols 2..15 are zero weights); wave w -> m-tile w.
__device__ __forceinline__ void layer_off(const unsigned short* lin, float* offb,
                                          const unsigned short* __restrict__ W,
                                          const float* __restrict__ bias, int w, int lane)
{
  int lm = lane & 15, quad = lane >> 4;
  float bv = (lm < 2) ? bias[lm] : 0.f;
  f32x4 acc = {bv, bv, bv, bv};
  #pragma unroll
  for (int kk = 0; kk < 8; kk++) {
    bf16x8 bf = *(const bf16x8*)(W + lm * 256 + kk * 32 + quad * 8);
    bf16x8 af = *(const bf16x8*)(lin + (w * 16 + lm) * KPAD + kk * 32 + quad * 8);
    acc = __builtin_amdgcn_mfma_f32_16x16x32_bf16(af, bf, acc, 0, 0, 0);
  }
  if (lm < 2) {
    #pragma unroll
    for (int r = 0; r < 4; r++) offb[(w * 16 + quad * 4 + r) * 2 + lm] = acc[r];
  }
}

// ---------------- fused LIIF kernel ----------------------------------------------
// Single in-place activation buffer (acc lives in registers across the read->write
// barrier) -> LDS 48.6 KB -> 3 blocks/CU.
__launch_bounds__(256, 3)
__global__ void liif_fused(const float* __restrict__ x, const unsigned short* __restrict__ wt,
                           const float* __restrict__ b0, const float* __restrict__ b1,
                           const float* __restrict__ b2, const float* __restrict__ rb0,
                           const float* __restrict__ rb1, const float* __restrict__ ob0,
                           const float* __restrict__ ob1, float* __restrict__ out)
{
  __shared__ __align__(16) unsigned short act[MT * KPAD];    // 33792 B
  __shared__ __align__(16) unsigned short predb[MT * PSTR];  // 5120 B
  __shared__ float routbuf[MT * 33];                         // 8448 B
  __shared__ float offb[MT * 2];
  __shared__ float gxy[MT * 2];

  int t = threadIdx.x;
  int ql = t & 63;            // lane == local query
  int g = t >> 6;             // wave id == 8-channel group
  int q = blockIdx.x * MT + ql;
  int b = q >> 16;            // / QQ
  int qi = q & (QQ - 1);
  int oy = qi >> 8;           // / WO
  int ox = qi & (WO - 1);

  float coordy = -1.f + (2.f * oy + 1.f) * (1.f / HO);
  float coordx = -1.f + (2.f * ox + 1.f) * (1.f / WO);
  float gy = fminf(fmaxf(coordy, -1.f + 1e-6f), 1.f - 1e-6f);
  float gx = fminf(fmaxf(coordx, -1.f + 1e-6f), 1.f - 1e-6f);

  const float* bptr = x + (b * CCH + g * 8) * HWH;

  // ---- phase 0: bicubic q_feat + analytic q_coord -> LDS bf16 input [64][36->64]
  {
    float feat[8], qcy, qcx;
    bicubic8(bptr, gx, gy, feat, qcy, qcx);
    union { uint32_t u[4]; bf16x8 v; } pk;
    #pragma unroll
    for (int c = 0; c < 4; c++) pk.u[c] = pkbf(feat[2 * c], feat[2 * c + 1]);
    *(bf16x8*)&act[ql * KPAD + g * 8] = pk.v;
    if (g == 0) {
      gxy[ql * 2 + 0] = gx;
      gxy[ql * 2 + 1] = gy;
      float rcy = (coordy - qcy) * (float)HH;
      float rcx = (coordx - qcx) * (float)WW;
      // faithful LIIF-quirk: cell[:,0] (query 0) *= 2/Ho ; cell[:,1] (query 1) *= 2/Wo
      float m = (qi == 0) ? (2.f / HO) : (qi == 1) ? (2.f / WO) : 1.f;
      act[ql * KPAD + 32] = f2bf(rcy);
      act[ql * KPAD + 33] = f2bf(rcx);
      act[ql * KPAD + 34] = f2bf(m * (float)HH);
      act[ql * KPAD + 35] = f2bf(m * (float)WW);
      for (int k = 36; k < 64; k++) act[ql * KPAD + k] = 0;
    }
  }
  __syncthreads();                                                        // B0

  // ---- MLP chain, single in-place activation buffer
  layer_n256<64, KPAD, true, true>(act, act, wt + WOFF_L0, b0, g, ql);    // inp -> h0
  __syncthreads();                                                        // B1
  layer_n256<256, KPAD, true, true>(act, act, wt + WOFF_L1, b1, g, ql);   // h0 -> h1
  __syncthreads();                                                        // B2
  layer_n32<256, false, 0>(act, predb, nullptr, wt + WOFF_L2, b2, g, ql); // h1 -> pred
  __syncthreads();                                                        // B3
  layer_n256<32, PSTR, true, false>(predb, act, wt + WOFF_R0, rb0, g, ql); // pred -> r0
  __syncthreads();                                                        // B4
  layer_n32<256, false, 1>(act, nullptr, routbuf, wt + WOFF_R1, rb1, g, ql); // r0 -> routing
  __syncthreads();                                                        // B5
  layer_n256<32, PSTR, true, false>(predb, act, wt + WOFF_O0, ob0, g, ql); // pred -> o0
  __syncthreads();                                                        // B6
  layer_off(act, offb, wt + WOFF_O1, ob1, g, ql);                         // o0 -> off
  __syncthreads();                                                        // B7

  // ---- final: resample at offset coords, modulate by routing, store
  {
    float gx2 = gxy[ql * 2 + 0] + offb[ql * 2 + 0];
    float gy2 = gxy[ql * 2 + 1] + offb[ql * 2 + 1];
    float feat[8], d0, d1;
    bicubic8(bptr, gx2, gy2, feat, d0, d1);
    float* op = out + (b * CCH + g * 8) * (HO * WO) + oy * WO + ox;
    #pragma unroll
    for (int c = 0; c < 8; c++)
      op[c * (HO * WO)] = feat[c] * (1.f + routbuf[ql * 33 + g * 8 + c]);
  }
}

extern "C" void kernel_launch(void* const* d_in, const int* in_sizes, int n_in,
                              void* d_out, int out_size, void* d_ws, size_t ws_size,
                              hipStream_t stream)
{
  const float* x   = (const float*)d_in[0];
  const float* w0  = (const float*)d_in[1];
  const float* b0  = (const float*)d_in[2];
  const float* w1  = (const float*)d_in[3];
  const float* b1  = (const float*)d_in[4];
  const float* w2  = (const float*)d_in[5];
  const float* b2  = (const float*)d_in[6];
  const float* r0  = (const float*)d_in[7];
  const float* rb0 = (const float*)d_in[8];
  const float* r1  = (const float*)d_in[9];
  const float* rb1 = (const float*)d_in[10];
  const float* o0  = (const float*)d_in[11];
  const float* ob0 = (const float*)d_in[12];
  const float* o1  = (const float*)d_in[13];
  const float* ob1 = (const float*)d_in[14];
  unsigned short* wt = (unsigned short*)d_ws;
  float* out = (float*)d_out;

  prep_weights<<<(WTOT + 255) / 256, 256, 0, stream>>>(w0, w1, w2, r0, r1, o0, o1, wt);
  liif_fused<<<(BB * QQ) / MT, 256, 0, stream>>>(x, wt, b0, b1, b2, rb0, rb1, ob0, ob1, out);
}